// Round 5
// baseline (116.042 us; speedup 1.0000x reference)
//
#include <hip/hip_runtime.h>

// GCN B=2, N=8192, F=64, O=64 — fp32. adj[b,i,j] = si_i + sj_j + c is
// rank-structured => layer collapses to O(B*N*F):
//   deg_i = N*(si_i + c) + SjT_b,  d_i = rsqrt(max(deg_i,1))
//   out[i,o] = relu( d_i*((si_i+c)*U[o] + V[o]) + bias_o )
//   U = (Σ_j d_j x_j) @ W,   V = (Σ_j sj_j d_j x_j) @ W
// SINGLE kernel, x read from HBM exactly once (64x64 tile lives in LDS across
// phases). Cross-block reductions via agent-scope atomics + flag-array spin
// barriers (cg::grid.sync measured ~50us/sync in R2 — hand-rolled is ~1-2us).
// 256 blocks x 256 thr: always fully co-resident (4 waves, ~20KB LDS/block,
// 256 CUs) => spin barrier cannot deadlock.

#define NN 8192
#define FF 64
#define TAG1 1u
#define TAG2 2u

__device__ inline void st_agent_f(float* p, float v) {
    __hip_atomic_store(p, v, __ATOMIC_RELAXED, __HIP_MEMORY_SCOPE_AGENT);
}
__device__ inline float ld_agent_f(const float* p) {
    return __hip_atomic_load(p, __ATOMIC_RELAXED, __HIP_MEMORY_SCOPE_AGENT);
}
__device__ inline void st_flag(unsigned* p, unsigned v) {
    __hip_atomic_store(p, v, __ATOMIC_RELEASE, __HIP_MEMORY_SCOPE_AGENT);
}
__device__ inline unsigned ld_flag(unsigned* p) {
    return __hip_atomic_load(p, __ATOMIC_ACQUIRE, __HIP_MEMORY_SCOPE_AGENT);
}

__global__ __launch_bounds__(256) void gcn_one(
    const float* __restrict__ x,      // (2,8192,64)
    const float* __restrict__ adj_w,  // (128,)
    const float* __restrict__ adj_b,  // (1,)
    const float* __restrict__ weight, // (64,64)
    const float* __restrict__ bias,   // (64,)
    float* __restrict__ out,          // (2,8192,64)
    float* __restrict__ parts1,       // 256
    float* __restrict__ p2,           // 256*64
    float* __restrict__ q2,           // 256*64
    unsigned* __restrict__ flags1,    // 256 (zeroed by memset)
    unsigned* __restrict__ flags2)    // 256 (zeroed by memset)
{
    __shared__ float xs[64 * FF];              // 16 KB x-tile
    __shared__ float wjs[FF], wis[FF];
    __shared__ float sis[64], sjs[64], dsh[64], sjd[64];
    __shared__ float red[128];
    __shared__ float pacc[256], qacc[256];
    __shared__ float ps[64], qs[64], Us[64], Vs[64];
    __shared__ float SjTs;

    const int tid = threadIdx.x;
    const int blk = blockIdx.x;                // 0..255
    const int batch = blk >> 7;                // 128 blocks/batch
    const int rowbase = blk * 64;

    if (tid < 2 * FF) {
        float v = adj_w[tid];
        if (tid < FF) wjs[tid] = v; else wis[tid - FF] = v;
    }
    __syncthreads();

    const int q4 = tid & 15, rl = tid >> 4;
    const float4 wjv = reinterpret_cast<const float4*>(wjs)[q4];
    const float4 wiv = reinterpret_cast<const float4*>(wis)[q4];

    // ---- Phase A: stage tile, per-row si/sj, block-partial Σsj ----
    #pragma unroll
    for (int pass = 0; pass < 4; ++pass) {
        int r = pass * 16 + rl;
        float4 xv = reinterpret_cast<const float4*>(x + (size_t)(rowbase + r) * FF)[q4];
        reinterpret_cast<float4*>(xs + r * FF)[q4] = xv;
        float a = xv.x * wjv.x + xv.y * wjv.y + xv.z * wjv.z + xv.w * wjv.w;
        float b = xv.x * wiv.x + xv.y * wiv.y + xv.z * wiv.z + xv.w * wiv.w;
        #pragma unroll
        for (int s = 8; s; s >>= 1) {
            a += __shfl_down(a, s, 16);
            b += __shfl_down(b, s, 16);
        }
        if (q4 == 0) { sjs[r] = a; sis[r] = b; }
    }
    __syncthreads();
    if (tid < 64) {
        float a = sjs[tid];
        #pragma unroll
        for (int s = 32; s; s >>= 1) a += __shfl_down(a, s, 64);
        if (tid == 0) st_agent_f(&parts1[blk], a);
    }
    // ---- barrier 1 (per batch): __syncthreads drains vmcnt(0) first ----
    __syncthreads();
    if (tid == 0) st_flag(&flags1[blk], TAG1);
    if (tid < 128) {
        unsigned* fl = &flags1[batch * 128 + tid];
        while (ld_flag(fl) != TAG1) __builtin_amdgcn_s_sleep(1);
    }
    __syncthreads();

    // ---- Phase B: SjT, d per row, block-partial p/q from LDS tile ----
    if (tid < 128) red[tid] = ld_agent_f(&parts1[batch * 128 + tid]);
    __syncthreads();
    if (tid < 64) {
        float a = red[tid] + red[tid + 64];
        #pragma unroll
        for (int s = 32; s; s >>= 1) a += __shfl_down(a, s, 64);
        if (tid == 0) SjTs = a;
    }
    __syncthreads();
    const float cadj = adj_b[0];
    if (tid < 64) {
        float d = rsqrtf(fmaxf(8192.f * (sis[tid] + cadj) + SjTs, 1.f));
        dsh[tid] = d; sjd[tid] = sjs[tid] * d;
    }
    __syncthreads();
    const int f = tid & 63, g = tid >> 6;
    {
        float pa = 0.f, qa = 0.f;
        #pragma unroll
        for (int r = g; r < 64; r += 4) {
            float xv = xs[r * FF + f];
            pa += dsh[r] * xv;
            qa += sjd[r] * xv;
        }
        pacc[tid] = pa; qacc[tid] = qa;
    }
    __syncthreads();
    if (tid < 64) {
        st_agent_f(&p2[blk * 64 + tid], pacc[tid] + pacc[tid + 64] + pacc[tid + 128] + pacc[tid + 192]);
        st_agent_f(&q2[blk * 64 + tid], qacc[tid] + qacc[tid + 64] + qacc[tid + 128] + qacc[tid + 192]);
    }
    // ---- barrier 2 ----
    __syncthreads();
    if (tid == 0) st_flag(&flags2[blk], TAG2);
    if (tid < 128) {
        unsigned* fl = &flags2[batch * 128 + tid];
        while (ld_flag(fl) != TAG2) __builtin_amdgcn_s_sleep(1);
    }
    __syncthreads();

    // ---- Phase C: batch-wide p,q (L2-hot, 32KB) then U,V matvec ----
    {
        float pa = 0.f, qa = 0.f;
        for (int b2 = g; b2 < 128; b2 += 4) {
            size_t idx = (size_t)(batch * 128 + b2) * 64 + f;
            pa += ld_agent_f(&p2[idx]);
            qa += ld_agent_f(&q2[idx]);
        }
        pacc[tid] = pa; qacc[tid] = qa;
    }
    __syncthreads();
    if (tid < 64) {
        ps[tid] = pacc[tid] + pacc[tid + 64] + pacc[tid + 128] + pacc[tid + 192];
        qs[tid] = qacc[tid] + qacc[tid + 64] + qacc[tid + 128] + qacc[tid + 192];
    }
    __syncthreads();
    if (tid < 128) {
        int sel = tid >> 6, o = tid & 63;
        const float* src = sel ? qs : ps;
        float s = 0.f;
        #pragma unroll
        for (int k = 0; k < FF; ++k) s += src[k] * weight[k * 64 + o];
        (sel ? Vs : Us)[o] = s;
    }
    __syncthreads();

    // ---- Phase D: epilogue, float4 stores ----
    const float4 bv = reinterpret_cast<const float4*>(bias)[q4];
    const float4 Uv = reinterpret_cast<const float4*>(Us)[q4];
    const float4 Vv = reinterpret_cast<const float4*>(Vs)[q4];
    #pragma unroll
    for (int pass = 0; pass < 4; ++pass) {
        int r = pass * 16 + rl;
        float d = dsh[r];
        float a = d * (sis[r] + cadj);
        float4 o;
        o.x = fmaxf(a * Uv.x + d * Vv.x + bv.x, 0.f);
        o.y = fmaxf(a * Uv.y + d * Vv.y + bv.y, 0.f);
        o.z = fmaxf(a * Uv.z + d * Vv.z + bv.z, 0.f);
        o.w = fmaxf(a * Uv.w + d * Vv.w + bv.w, 0.f);
        reinterpret_cast<float4*>(out + (size_t)(rowbase + r) * FF)[q4] = o;
    }
}

extern "C" void kernel_launch(void* const* d_in, const int* in_sizes, int n_in,
                              void* d_out, int out_size, void* d_ws, size_t ws_size,
                              hipStream_t stream) {
    const float* x      = (const float*)d_in[0];
    const float* adj_w  = (const float*)d_in[1];
    const float* adj_b  = (const float*)d_in[2];
    const float* weight = (const float*)d_in[3];
    const float* bias   = (const float*)d_in[4];
    float* out = (float*)d_out;

    float*    ws     = (float*)d_ws;
    float*    parts1 = ws;                         // 256
    float*    p2     = ws + 256;                   // 16384
    float*    q2     = ws + 256 + 16384;           // 16384
    unsigned* flags1 = (unsigned*)(ws + 256 + 2 * 16384);   // 256
    unsigned* flags2 = flags1 + 256;                        // 256

    // barrier flags must start != TAG on every call (ws is poisoned 0xAA,
    // and state on the correctness call is unspecified) — 2KB fill is cheap
    hipMemsetAsync(flags1, 0, 512 * sizeof(unsigned), stream);

    void* args[] = { (void*)&x, (void*)&adj_w, (void*)&adj_b, (void*)&weight,
                     (void*)&bias, (void*)&out, (void*)&parts1, (void*)&p2,
                     (void*)&q2, (void*)&flags1, (void*)&flags2 };
    hipLaunchKernelGGL(gcn_one, dim3(256), dim3(256), 0, stream,
                       x, adj_w, adj_b, weight, bias, out,
                       parts1, p2, q2, flags1, flags2);
    (void)args;
}

// Round 7
// 82.726 us; speedup vs baseline: 1.4027x; 1.4027x over previous
//
#include <hip/hip_runtime.h>

// GCN B=2, N=8192, F=64, O=64 — fp32. adj[b,i,j] = si_i + sj_j + c is
// rank-structured => layer collapses to O(B*N*F):
//   deg_i = N*(si_i + c) + SjT_b,  d_i = rsqrt(max(deg_i,1))
//   out[i,o] = relu( d_i*(si_i+c)*U[o] + d_i*V[o] + bias_o )
//   U = (Σ_j d_j x_j) @ W,   V = (Σ_j sj_j d_j x_j) @ W
// 3 stream-ordered kernels. Kernel boundary = global sync (~2-3µs); in-kernel
// device-wide sync measured ~25µs/sync on gfx950 (R2 cg::grid.sync AND R4
// hand-rolled flag barrier agree) — do not fuse.
// No atomics, no ws zeroing: all workspace is write-before-read.

#define NN 8192
#define FF 64

typedef float f4 __attribute__((ext_vector_type(4)));  // clang-native vec for nontemporal builtins

// K1: 256 blocks x 256 thr, 64 rows/block. Per-row si/sj + block-partial Σsj.
__global__ __launch_bounds__(256) void k1_sisj(const float* __restrict__ x,
                                               const float* __restrict__ adj_w,
                                               float* __restrict__ si,
                                               float* __restrict__ sj,
                                               float* __restrict__ parts1) {
    __shared__ float wjs[FF], wis[FF], sjs[64];
    int tid = threadIdx.x;
    if (tid < 2 * FF) {
        float v = adj_w[tid];
        if (tid < FF) wjs[tid] = v; else wis[tid - FF] = v;
    }
    __syncthreads();
    int q4 = tid & 15, rl = tid >> 4;
    float4 wjv = reinterpret_cast<const float4*>(wjs)[q4];
    float4 wiv = reinterpret_cast<const float4*>(wis)[q4];
    int rowbase = blockIdx.x * 64;
    #pragma unroll
    for (int pass = 0; pass < 4; ++pass) {
        int r = pass * 16 + rl;
        int row = rowbase + r;
        float4 xv = reinterpret_cast<const float4*>(x + (size_t)row * FF)[q4];
        float a = xv.x * wjv.x + xv.y * wjv.y + xv.z * wjv.z + xv.w * wjv.w;
        float b = xv.x * wiv.x + xv.y * wiv.y + xv.z * wiv.z + xv.w * wiv.w;
        #pragma unroll
        for (int s = 8; s; s >>= 1) {
            a += __shfl_down(a, s, 16);
            b += __shfl_down(b, s, 16);
        }
        if (q4 == 0) { sj[row] = a; si[row] = b; sjs[r] = a; }
    }
    __syncthreads();
    if (tid < 64) {
        float a = sjs[tid];
        #pragma unroll
        for (int s = 32; s; s >>= 1) a += __shfl_down(a, s, 64);
        if (tid == 0) parts1[blockIdx.x] = a;   // 128 per batch
    }
}

// K2: 128 blocks x 256 thr, 128 rows/block. SjT (redundant per block), per-row
// rowinfo=(d, a=d*(si+c)) for K3, block-partial p/q.
__global__ __launch_bounds__(256) void k2_pq(const float* __restrict__ x,
                                             const float* __restrict__ adj_b,
                                             const float* __restrict__ si,
                                             const float* __restrict__ sj,
                                             const float* __restrict__ parts1,
                                             float2* __restrict__ rowinfo,
                                             float* __restrict__ p2,
                                             float* __restrict__ q2) {
    __shared__ float red[128], dsh[128], sjdsh[128];
    __shared__ float pacc[256], qacc[256];
    __shared__ float SjTs;
    int tid = threadIdx.x;
    int batch = blockIdx.x >> 6;                 // 64 blocks/batch
    int base = batch * NN + (blockIdx.x & 63) * 128;
    if (tid < 128) red[tid] = parts1[batch * 128 + tid];
    __syncthreads();
    if (tid < 64) {
        float a = red[tid] + red[tid + 64];
        #pragma unroll
        for (int s = 32; s; s >>= 1) a += __shfl_down(a, s, 64);
        if (tid == 0) SjTs = a;
    }
    __syncthreads();
    float cadj = adj_b[0];
    if (tid < 128) {
        int row = base + tid;
        float siv = si[row], sjv = sj[row];
        float d = rsqrtf(fmaxf(8192.f * (siv + cadj) + SjTs, 1.f));
        dsh[tid] = d; sjdsh[tid] = sjv * d;
        rowinfo[row] = make_float2(d, d * (siv + cadj));
    }
    __syncthreads();
    int f = tid & 63, g = tid >> 6;
    float pa = 0.f, qa = 0.f;
    for (int r = g; r < 128; r += 4) {
        float xv = __builtin_nontemporal_load(x + (size_t)(base + r) * FF + f);
        pa += dsh[r] * xv;
        qa += sjdsh[r] * xv;
    }
    pacc[tid] = pa; qacc[tid] = qa;
    __syncthreads();
    if (tid < 64) {
        p2[blockIdx.x * 64 + tid] = pacc[tid] + pacc[tid + 64] + pacc[tid + 128] + pacc[tid + 192];
        q2[blockIdx.x * 64 + tid] = qacc[tid] + qacc[tid + 64] + qacc[tid + 128] + qacc[tid + 192];
    }
}

// K3: 256 blocks x 256 thr, 64 rows/block. Reduce parts2 (redundant, L2-hot),
// U/V matvec, epilogue with nontemporal float4 stores.
__global__ __launch_bounds__(256) void k3_out(const float* __restrict__ weight,
                                              const float* __restrict__ bias,
                                              const float2* __restrict__ rowinfo,
                                              const float* __restrict__ p2,
                                              const float* __restrict__ q2,
                                              float* __restrict__ out) {
    __shared__ float pacc[256], qacc[256];
    __shared__ float ps[64], qs[64], Us[64], Vs[64];
    __shared__ float2 ri[64];
    int tid = threadIdx.x;
    int batch = blockIdx.x >> 7;                 // 128 blocks/batch
    int rowbase = blockIdx.x * 64;
    if (tid < 64) ri[tid] = rowinfo[rowbase + tid];
    int f = tid & 63, g = tid >> 6;
    float pa = 0.f, qa = 0.f;
    for (int b2 = g; b2 < 64; b2 += 4) {         // 64 K2-blocks per batch
        size_t idx = (size_t)(batch * 64 + b2) * 64 + f;
        pa += p2[idx];
        qa += q2[idx];
    }
    pacc[tid] = pa; qacc[tid] = qa;
    __syncthreads();
    if (tid < 64) {
        ps[tid] = pacc[tid] + pacc[tid + 64] + pacc[tid + 128] + pacc[tid + 192];
        qs[tid] = qacc[tid] + qacc[tid + 64] + qacc[tid + 128] + qacc[tid + 192];
    }
    __syncthreads();
    if (tid < 128) {
        int sel = tid >> 6, o = tid & 63;
        const float* src = sel ? qs : ps;
        float s = 0.f;
        #pragma unroll
        for (int k = 0; k < FF; ++k) s += src[k] * weight[k * 64 + o];
        (sel ? Vs : Us)[o] = s;
    }
    __syncthreads();
    int q4 = tid & 15, rl = tid >> 4;
    float4 bv = reinterpret_cast<const float4*>(bias)[q4];
    float4 Uv = reinterpret_cast<const float4*>(Us)[q4];
    float4 Vv = reinterpret_cast<const float4*>(Vs)[q4];
    #pragma unroll
    for (int pass = 0; pass < 4; ++pass) {
        int r = pass * 16 + rl;
        int row = rowbase + r;
        float d = ri[r].x, a = ri[r].y;
        f4 o;
        o.x = fmaxf(a * Uv.x + d * Vv.x + bv.x, 0.f);
        o.y = fmaxf(a * Uv.y + d * Vv.y + bv.y, 0.f);
        o.z = fmaxf(a * Uv.z + d * Vv.z + bv.z, 0.f);
        o.w = fmaxf(a * Uv.w + d * Vv.w + bv.w, 0.f);
        __builtin_nontemporal_store(o, reinterpret_cast<f4*>(out + (size_t)row * FF) + q4);
    }
}

extern "C" void kernel_launch(void* const* d_in, const int* in_sizes, int n_in,
                              void* d_out, int out_size, void* d_ws, size_t ws_size,
                              hipStream_t stream) {
    const float* x      = (const float*)d_in[0];   // (2,8192,64)
    const float* adj_w  = (const float*)d_in[1];   // (128,)
    const float* adj_b  = (const float*)d_in[2];   // (1,)
    const float* weight = (const float*)d_in[3];   // (64,64)
    const float* bias   = (const float*)d_in[4];   // (64,)
    float* out = (float*)d_out;                    // (2,8192,64)

    float*  ws      = (float*)d_ws;
    float*  si      = ws;                 // 16384
    float*  sj      = ws + 16384;         // 16384
    float2* rowinfo = (float2*)(ws + 32768);   // 16384 rows x float2
    float*  parts1  = ws + 65536;         // 256
    float*  p2      = ws + 65792;         // 8192
    float*  q2      = ws + 73984;         // 8192

    k1_sisj<<<256, 256, 0, stream>>>(x, adj_w, si, sj, parts1);
    k2_pq  <<<128, 256, 0, stream>>>(x, adj_b, si, sj, parts1, rowinfo, p2, q2);
    k3_out <<<256, 256, 0, stream>>>(weight, bias, rowinfo, p2, q2, out);
}